// Round 17
// baseline (119.621 us; speedup 1.0000x reference)
//
#include <hip/hip_runtime.h>
#include <hip/hip_bf16.h>

#define BATCH 4096
#define IN_DIM 3072
#define HID 1024
#define NSTEP 6

typedef __attribute__((ext_vector_type(8))) short short8;
typedef __attribute__((ext_vector_type(4))) float f32x4;
typedef __attribute__((ext_vector_type(4))) unsigned short ushort4v;

__device__ __forceinline__ void gload_lds16(const void* g, void* lds) {
  __builtin_amdgcn_global_load_lds(
      (const __attribute__((address_space(1))) void*)g,
      (__attribute__((address_space(3))) void*)lds, 16, 0, 0);
}

__device__ __forceinline__ unsigned short f32_to_bf16(float f) {
  unsigned int u = __builtin_bit_cast(unsigned int, f);
  unsigned int r = u + 0x7fffu + ((u >> 16) & 1u);
  return (unsigned short)(r >> 16);
}

#define BARX()                          \
  do {                                  \
    asm volatile("" ::: "memory");      \
    __builtin_amdgcn_s_barrier();       \
    __builtin_amdgcn_sched_barrier(0);  \
  } while (0)

#define VMCNT(N)                                            \
  do {                                                      \
    asm volatile("s_waitcnt vmcnt(" #N ")" ::: "memory");   \
    __builtin_amdgcn_sched_barrier(0);                      \
  } while (0)

// BK=32 granule swizzle (residual 2-way aliasing only — free, m136)
__device__ __forceinline__ int swz4(int r) { return (r & 3) ^ ((r >> 2) & 3); }

// fused f32 -> bf16 conversion of x, We, Wd (one launch)
__global__ void cvt3_kernel(const float* __restrict__ a,
                            const float* __restrict__ b,
                            const float* __restrict__ c,
                            unsigned short* __restrict__ da,
                            unsigned short* __restrict__ db,
                            unsigned short* __restrict__ dc, int na, int nb,
                            int nc) {
  const int total = na + nb + nc;
  const int stride = gridDim.x * blockDim.x;
  for (int i = blockIdx.x * blockDim.x + threadIdx.x; i < total; i += stride) {
    const float* s;
    unsigned short* d;
    int j = i;
    if (j < na) {
      s = a; d = da;
    } else if (j < na + nb) {
      s = b; d = db; j -= na;
    } else {
      s = c; d = dc; j -= na + nb;
    }
    const float4 v = reinterpret_cast<const float4*>(s)[j];
    ushort4v o;
    o.x = f32_to_bf16(v.x);
    o.y = f32_to_bf16(v.y);
    o.z = f32_to_bf16(v.z);
    o.w = f32_to_bf16(v.w);
    reinterpret_cast<ushort4v*>(d)[j] = o;
  }
}

// Split-K2 reduce (p0+p1+bias) + RK4 nmODE. Writes y f32 (NT) + bf16.
__global__ __launch_bounds__(256) void ode_kernel(
    const float* __restrict__ p0, const float* __restrict__ p1,
    const float* __restrict__ be, float* __restrict__ hid,
    unsigned short* __restrict__ hb, int n4) {
  const float dt = 1.0f / (float)NSTEP;
  const float h2 = 0.5f * dt, hd = dt, h6 = dt / 6.0f;
  int stride = gridDim.x * blockDim.x;
  for (int i = blockIdx.x * blockDim.x + threadIdx.x; i < n4; i += stride) {
    const float4 a4 = reinterpret_cast<const float4*>(p0)[i];
    const float4 b4 = reinterpret_cast<const float4*>(p1)[i];
    const float4 e4 = reinterpret_cast<const float4*>(be)[i & (HID / 4 - 1)];
    float g[4] = {a4.x + b4.x + e4.x, a4.y + b4.y + e4.y,
                  a4.z + b4.z + e4.z, a4.w + b4.w + e4.w};
    float y[4] = {0.0f, 0.0f, 0.0f, 0.0f};
#pragma unroll 1
    for (int s = 0; s < NSTEP; ++s) {
      float k1[4], k2[4], k3[4], k4[4];
#pragma unroll
      for (int e = 0; e < 4; ++e) {
        float t = __sinf(y[e] + g[e]);
        k1[e] = t * t - y[e];
      }
#pragma unroll
      for (int e = 0; e < 4; ++e) {
        float yy = fmaf(h2, k1[e], y[e]);
        float t = __sinf(yy + g[e]);
        k2[e] = t * t - yy;
      }
#pragma unroll
      for (int e = 0; e < 4; ++e) {
        float yy = fmaf(h2, k2[e], y[e]);
        float t = __sinf(yy + g[e]);
        k3[e] = t * t - yy;
      }
#pragma unroll
      for (int e = 0; e < 4; ++e) {
        float yy = fmaf(hd, k3[e], y[e]);
        float t = __sinf(yy + g[e]);
        k4[e] = t * t - yy;
      }
#pragma unroll
      for (int e = 0; e < 4; ++e) {
        float ks = k1[e] + 2.0f * (k2[e] + k3[e]) + k4[e];
        y[e] = fmaf(h6, ks, y[e]);
      }
    }
    f32x4 o4;
    o4[0] = y[0]; o4[1] = y[1]; o4[2] = y[2]; o4[3] = y[3];
    __builtin_nontemporal_store(o4, &reinterpret_cast<f32x4*>(hid)[i]);
    ushort4v ob;
    ob.x = f32_to_bf16(y[0]);
    ob.y = f32_to_bf16(y[1]);
    ob.z = f32_to_bf16(y[2]);
    ob.w = f32_to_bf16(y[3]);
    reinterpret_cast<ushort4v*>(hb)[i] = ob;
  }
}

// Deep-prefetch 3-buffer NT GEMM. 128x128 tile, BK=32, 4 waves (2x2),
// 48 KB LDS (3 x 16 KB buffer pairs) -> up to 3 blocks/CU.
// Per iter: STAGE(t+2) -> vmcnt(8) [retires ONLY tile t's 4 loads; tiles
// t+1,t+2 stay in flight ~2 iters = full HBM latency cover] -> barrier ->
// reads+MFMA -> barrier. No vmcnt(0) drain anywhere in the loop.
// Safety: staged buffer (t+2)%3 was last read in iter t-1, ordered by the
// trailing barrier; tail iters dummy-stage (k0=0) to keep the in-order
// vmcnt retirement count uniform; no other vmem ops inside the loop.
// Swizzle rule #21 (linear gload_lds dest + inverse-swizzled source +
// swizzled ds_read, swz4). EPI=0: f32 partial at Cout + sk*BATCH*HID.
// EPI=1: bias + sigmoid, NT f32 store.
template <int KSTRIDE, int NSK, int NBN, int NOUT, int EPI>
__global__ __launch_bounds__(256) void gemm3b(
    const unsigned short* __restrict__ A, const unsigned short* __restrict__ B,
    const float* __restrict__ bias, float* __restrict__ Cout) {
  constexpr int BM = 128, BN = 128, BK = 32;
  constexpr int KLEN = KSTRIDE / NSK;
  constexpr int ntT = KLEN / BK;
  constexpr int nbm = BATCH / BM;
  constexpr int tiles = nbm * NBN;

  __shared__ unsigned short As[3][BM * BK];
  __shared__ unsigned short Bs[3][BN * BK];

  const int tid = threadIdx.x;
  const int wave = tid >> 6;
  const int lane = tid & 63;
  const int wrow = wave >> 1, wcol = wave & 1;

  // chunked XCD swizzle (grid divisible by 8); bn-fastest, sk-slowest
  const int nwg = gridDim.x;
  const int swz = (blockIdx.x & 7) * (nwg >> 3) + (blockIdx.x >> 3);
  const int sk = swz / tiles;
  const int rem = swz % tiles;
  const int bn = rem % NBN;
  const int bm = rem / NBN;

  const unsigned short* Ablk = A + (size_t)bm * BM * KSTRIDE + sk * KLEN;
  const unsigned short* Bblk = B + (size_t)bn * BN * KSTRIDE + sk * KLEN;

  const int srow = tid >> 2;  // 0..63: row within a 64-row round
  const int sgr = tid & 3;    // logical 16B granule

  // 4 wave-uniform rounds: r=0,1 -> A rows {0..63},{64..127}; r=2,3 -> B.
  auto STAGE = [&](int buf, int k0) {
#pragma unroll
    for (int r = 0; r < 4; ++r) {
      const int rr = srow + (r & 1) * 64;
      const int g = sgr ^ swz4(rr);  // inverse-swizzled global source
      if (r < 2)
        gload_lds16(Ablk + (size_t)rr * KSTRIDE + k0 + g * 8,
                    (void*)&As[buf][(r & 1) * 2048 + tid * 8]);
      else
        gload_lds16(Bblk + (size_t)rr * KSTRIDE + k0 + g * 8,
                    (void*)&Bs[buf][(r & 1) * 2048 + tid * 8]);
    }
  };

  const int fr = lane & 15;
  const int hi = lane >> 4;

  f32x4 acc[4][4] = {};

  // prologue: tiles 0 and 1 in flight; retire tile 0 only (vmcnt(4))
  STAGE(0, 0);
  STAGE(1, BK);
  VMCNT(4);
  BARX();

  int bc = 0, bs = 2;
#pragma unroll 1
  for (int t = 0; t < ntT; ++t) {
    const int ks = (t + 2 < ntT) ? (t + 2) * BK : 0;  // dummy-stage on tail
    STAGE(bs, ks);
    VMCNT(8);  // retire tile t's loads; t+1, t+2 stay in flight
    BARX();

    short8 af[4], bfr[4];
#pragma unroll
    for (int m = 0; m < 4; ++m) {
      const int row = wrow * 64 + m * 16 + fr;
      const int g = hi ^ swz4(row);  // swizzled read granule
      af[m] = *reinterpret_cast<const short8*>(&As[bc][row * BK + g * 8]);
    }
#pragma unroll
    for (int n = 0; n < 4; ++n) {
      const int row = wcol * 64 + n * 16 + fr;
      const int g = hi ^ swz4(row);
      bfr[n] = *reinterpret_cast<const short8*>(&Bs[bc][row * BK + g * 8]);
    }
#pragma unroll
    for (int m = 0; m < 4; ++m)
#pragma unroll
      for (int n = 0; n < 4; ++n)
        acc[m][n] = __builtin_amdgcn_mfma_f32_16x16x32_bf16(af[m], bfr[n],
                                                            acc[m][n], 0, 0, 0);
    BARX();  // reads of buf bc done before it is restaged (iter t+1 stages bc+2)

    bc = (bc == 2) ? 0 : bc + 1;
    bs = (bs == 2) ? 0 : bs + 1;
  }

  // epilogue: C/D layout col=lane&15, row=(lane>>4)*4+reg (m89-verified)
  const int rowbase = bm * BM + wrow * 64 + hi * 4;
  const int colbase = bn * BN + wcol * 64 + fr;

  if constexpr (EPI == 0) {
    float* Cblk = Cout + (size_t)sk * BATCH * NOUT;
#pragma unroll
    for (int n = 0; n < 4; ++n)
#pragma unroll
      for (int m = 0; m < 4; ++m)
#pragma unroll
        for (int r = 0; r < 4; ++r) {
          size_t idx =
              (size_t)(rowbase + m * 16 + r) * NOUT + (colbase + n * 16);
          Cblk[idx] = acc[m][n][r];
        }
  } else {
#pragma unroll
    for (int n = 0; n < 4; ++n) {
      const float bv = bias[colbase + n * 16];
#pragma unroll
      for (int m = 0; m < 4; ++m)
#pragma unroll
        for (int r = 0; r < 4; ++r) {
          float v = acc[m][n][r] + bv;
          v = 1.0f / (1.0f + __expf(-v));
          size_t idx =
              (size_t)(rowbase + m * 16 + r) * NOUT + (colbase + n * 16);
          __builtin_nontemporal_store(v, &Cout[idx]);
        }
    }
  }
}

extern "C" void kernel_launch(void* const* d_in, const int* in_sizes, int n_in,
                              void* d_out, int out_size, void* d_ws,
                              size_t ws_size, hipStream_t stream) {
  const float* x = (const float*)d_in[0];
  const float* We = (const float*)d_in[1];
  const float* be = (const float*)d_in[2];
  const float* Wd = (const float*)d_in[3];
  const float* bd = (const float*)d_in[4];

  float* out = (float*)d_out;                 // [4096,3072]
  float* hid = out + (size_t)BATCH * IN_DIM;  // [4096,1024]
  // split-K=2 f32 partials (33.6MB) in the out region (50MB); GEMM2 last.
  float* part = out;

  unsigned short* xb = (unsigned short*)d_ws;          // bf16 x   [4096,3072]
  unsigned short* Web = xb + (size_t)BATCH * IN_DIM;   // bf16 We  [1024,3072]
  unsigned short* Wdb = Web + (size_t)HID * IN_DIM;    // bf16 Wd  [3072,1024]
  unsigned short* hb = Wdb + (size_t)IN_DIM * HID;     // bf16 hid [4096,1024]

  cvt3_kernel<<<2048, 256, 0, stream>>>(
      x, We, Wd, xb, Web, Wdb, BATCH * IN_DIM / 4, HID * IN_DIM / 4,
      IN_DIM * HID / 4);

  // GEMM1: deep-prefetch 3-buf, f32 partials of x @ We^T. split-K=2,
  // 512 blocks = 2/CU, 48 iters.
  gemm3b<IN_DIM, 2, HID / 128, HID, 0>
      <<<512, 256, 0, stream>>>(xb, Web, nullptr, part);

  // ODE: gamma = p0+p1+be, RK4 -> hid f32 (NT) + hb bf16
  ode_kernel<<<2048, 256, 0, stream>>>(part, part + (size_t)BATCH * HID, be,
                                       hid, hb, BATCH * HID / 4);

  // GEMM2: deep-prefetch 3-buf. 768 blocks = 3/CU, 32 iters.
  gemm3b<HID, 1, IN_DIM / 128, IN_DIM, 1>
      <<<768, 256, 0, stream>>>(hb, Wdb, bd, out);
}

// Round 19
// 114.640 us; speedup vs baseline: 1.0434x; 1.0434x over previous
//
#include <hip/hip_runtime.h>
#include <hip/hip_bf16.h>

#define BATCH 4096
#define IN_DIM 3072
#define HID 1024
#define NSTEP 6

typedef __attribute__((ext_vector_type(8))) short short8;
typedef __attribute__((ext_vector_type(4))) float f32x4;
typedef __attribute__((ext_vector_type(4))) unsigned short ushort4v;
typedef __attribute__((ext_vector_type(4))) int int4v;

__device__ __forceinline__ void gload_lds16(const void* g, void* lds) {
  __builtin_amdgcn_global_load_lds(
      (const __attribute__((address_space(1))) void*)g,
      (__attribute__((address_space(3))) void*)lds, 16, 0, 0);
}

__device__ __forceinline__ unsigned short f32_to_bf16(float f) {
  unsigned int u = __builtin_bit_cast(unsigned int, f);
  unsigned int r = u + 0x7fffu + ((u >> 16) & 1u);
  return (unsigned short)(r >> 16);
}

// pack 2 f32 -> u32 of 2 bf16 (RNE via the same rounding as f32_to_bf16)
__device__ __forceinline__ unsigned int pk2(float a, float b) {
  return (unsigned int)f32_to_bf16(a) | ((unsigned int)f32_to_bf16(b) << 16);
}

// BK=32 bf16 granule swizzle (2-way residual aliasing — free, m136)
__device__ __forceinline__ int swz4(int r) { return (r & 3) ^ ((r >> 2) & 3); }

// f32 -> bf16 conversion of We, Wd only (x is consumed f32 by GEMM1)
__global__ void cvt2_kernel(const float* __restrict__ a,
                            const float* __restrict__ b,
                            unsigned short* __restrict__ da,
                            unsigned short* __restrict__ db, int na, int nb) {
  const int total = na + nb;
  const int stride = gridDim.x * blockDim.x;
  for (int i = blockIdx.x * blockDim.x + threadIdx.x; i < total; i += stride) {
    const float* s;
    unsigned short* d;
    int j = i;
    if (j < na) {
      s = a; d = da;
    } else {
      s = b; d = db; j -= na;
    }
    const float4 v = reinterpret_cast<const float4*>(s)[j];
    ushort4v o;
    o.x = f32_to_bf16(v.x);
    o.y = f32_to_bf16(v.y);
    o.z = f32_to_bf16(v.z);
    o.w = f32_to_bf16(v.w);
    reinterpret_cast<ushort4v*>(d)[j] = o;
  }
}

// Split-K3 reduce (p0+p1+p2+bias) + RK4 nmODE. Writes y f32 (NT) + bf16.
__global__ __launch_bounds__(256) void ode3_kernel(
    const float* __restrict__ part, const float* __restrict__ be,
    float* __restrict__ hid, unsigned short* __restrict__ hb, int n4) {
  const float dt = 1.0f / (float)NSTEP;
  const float h2 = 0.5f * dt, hd = dt, h6 = dt / 6.0f;
  const size_t seg = (size_t)BATCH * HID / 4;
  const float4* p4 = reinterpret_cast<const float4*>(part);
  int stride = gridDim.x * blockDim.x;
  for (int i = blockIdx.x * blockDim.x + threadIdx.x; i < n4; i += stride) {
    const float4 a4 = p4[i];
    const float4 b4 = p4[i + seg];
    const float4 c4 = p4[i + 2 * seg];
    const float4 e4 = reinterpret_cast<const float4*>(be)[i & (HID / 4 - 1)];
    float g[4] = {a4.x + b4.x + c4.x + e4.x, a4.y + b4.y + c4.y + e4.y,
                  a4.z + b4.z + c4.z + e4.z, a4.w + b4.w + c4.w + e4.w};
    float y[4] = {0.0f, 0.0f, 0.0f, 0.0f};
#pragma unroll 1
    for (int s = 0; s < NSTEP; ++s) {
      float k1[4], k2[4], k3[4], k4[4];
#pragma unroll
      for (int e = 0; e < 4; ++e) {
        float t = __sinf(y[e] + g[e]);
        k1[e] = t * t - y[e];
      }
#pragma unroll
      for (int e = 0; e < 4; ++e) {
        float yy = fmaf(h2, k1[e], y[e]);
        float t = __sinf(yy + g[e]);
        k2[e] = t * t - yy;
      }
#pragma unroll
      for (int e = 0; e < 4; ++e) {
        float yy = fmaf(h2, k2[e], y[e]);
        float t = __sinf(yy + g[e]);
        k3[e] = t * t - yy;
      }
#pragma unroll
      for (int e = 0; e < 4; ++e) {
        float yy = fmaf(hd, k3[e], y[e]);
        float t = __sinf(yy + g[e]);
        k4[e] = t * t - yy;
      }
#pragma unroll
      for (int e = 0; e < 4; ++e) {
        float ks = k1[e] + 2.0f * (k2[e] + k3[e]) + k4[e];
        y[e] = fmaf(h6, ks, y[e]);
      }
    }
    f32x4 o4;
    o4[0] = y[0]; o4[1] = y[1]; o4[2] = y[2]; o4[3] = y[3];
    __builtin_nontemporal_store(o4, &reinterpret_cast<f32x4*>(hid)[i]);
    ushort4v ob;
    ob.x = f32_to_bf16(y[0]);
    ob.y = f32_to_bf16(y[1]);
    ob.z = f32_to_bf16(y[2]);
    ob.w = f32_to_bf16(y[3]);
    reinterpret_cast<ushort4v*>(hb)[i] = ob;
  }
}

// GEMM1: A staged DIRECTLY from f32 x via gload_lds (saves the 75MB cvt
// round-trip). 128x128, BK=32, 4 waves (2x2), split-K=3 -> 768 blocks =
// exactly 3/CU (48 KB LDS: A-f32 2x16KB + B-bf16 2x8KB). Fragments read
// as 2x ds_read_b128 f32 + 4x v_cvt_pk (in the stall shadow). A-swizzle:
// 8 granules/f32-row, proven row&7 XOR (2-way max). B: bf16, swz4.
// f32 partial at Cout + sk*BATCH*HID.
__global__ __launch_bounds__(256) void gemm1f(
    const float* __restrict__ X, const unsigned short* __restrict__ B,
    float* __restrict__ Cout) {
  constexpr int BM = 128, BN = 128, BK = 32;
  constexpr int Kstride = IN_DIM;    // 3072
  constexpr int Klen = Kstride / 3;  // 1024
  constexpr int ntT = Klen / BK;     // 32
  constexpr int nbn = HID / BN;      // 8
  constexpr int nbm = BATCH / BM;    // 32
  constexpr int tiles = nbm * nbn;   // 256

  __shared__ float As[2][BM * BK];            // 16 KB each
  __shared__ unsigned short Bs[2][BN * BK];   // 8 KB each

  const int tid = threadIdx.x;
  const int wave = tid >> 6;
  const int lane = tid & 63;
  const int wrow = wave >> 1, wcol = wave & 1;

  const int nwg = gridDim.x;  // 768
  const int swz = (blockIdx.x & 7) * (nwg >> 3) + (blockIdx.x >> 3);
  const int sk = swz / tiles;        // 0..2
  const int rem = swz % tiles;
  const int bn = rem % nbn;
  const int bm = rem / nbn;

  const float* Xblk = X + (size_t)bm * BM * Kstride + sk * Klen;
  const unsigned short* Bblk = B + (size_t)bn * BN * Kstride + sk * Klen;

  // A staging: 4 rounds of 32 rows; thread -> row tid>>3, phys granule tid&7
  const int arow = tid >> 3;  // 0..31
  const int agp = tid & 7;    // phys 16B granule (4 f32)
  // B staging: 2 rounds of 64 rows; thread -> row tid>>2, granule tid&3
  const int brow = tid >> 2;  // 0..63
  const int bgp = tid & 3;

  auto STAGE = [&](int buf, int k0) {
#pragma unroll
    for (int r = 0; r < 4; ++r) {
      const int rr = r * 32 + arow;
      const int gl = agp ^ (rr & 7);  // inverse-swizzled source granule
      gload_lds16(Xblk + (size_t)rr * Kstride + k0 + gl * 4,
                  (void*)&As[buf][rr * 32 + agp * 4]);
    }
#pragma unroll
    for (int r = 0; r < 2; ++r) {
      const int rr = r * 64 + brow;
      const int gl = bgp ^ swz4(rr);
      gload_lds16(Bblk + (size_t)rr * Kstride + k0 + gl * 8,
                  (void*)&Bs[buf][r * 2048 + tid * 8]);
    }
  };

  const int fr = lane & 15;
  const int hi = lane >> 4;

  f32x4 acc[4][4] = {};

  STAGE(0, 0);
#pragma unroll 1
  for (int t = 0; t < ntT; ++t) {
    const int buf = t & 1;
    __syncthreads();  // compiler drains vmcnt/lgkm: tile t resident
    if (t + 1 < ntT) STAGE(buf ^ 1, (t + 1) * BK);

    short8 af[4], bfr[4];
#pragma unroll
    for (int m = 0; m < 4; ++m) {
      const int row = wrow * 64 + m * 16 + fr;
      const int g0 = (hi * 2) ^ (row & 7);
      const int g1 = (hi * 2 + 1) ^ (row & 7);
      const float4 lo = *reinterpret_cast<const float4*>(
          &As[buf][row * 32 + g0 * 4]);
      const float4 h4 = *reinterpret_cast<const float4*>(
          &As[buf][row * 32 + g1 * 4]);
      int4v p;
      p.x = (int)pk2(lo.x, lo.y);
      p.y = (int)pk2(lo.z, lo.w);
      p.z = (int)pk2(h4.x, h4.y);
      p.w = (int)pk2(h4.z, h4.w);
      af[m] = __builtin_bit_cast(short8, p);
    }
#pragma unroll
    for (int n = 0; n < 4; ++n) {
      const int row = wcol * 64 + n * 16 + fr;
      const int g = hi ^ swz4(row);
      bfr[n] = *reinterpret_cast<const short8*>(&Bs[buf][row * BK + g * 8]);
    }
#pragma unroll
    for (int m = 0; m < 4; ++m)
#pragma unroll
      for (int n = 0; n < 4; ++n)
        acc[m][n] = __builtin_amdgcn_mfma_f32_16x16x32_bf16(af[m], bfr[n],
                                                            acc[m][n], 0, 0, 0);
  }

  // epilogue: C/D layout col=lane&15, row=(lane>>4)*4+reg (m89-verified)
  const int rowbase = bm * BM + wrow * 64 + hi * 4;
  const int colbase = bn * BN + wcol * 64 + fr;
  float* Cblk = Cout + (size_t)sk * BATCH * HID;
#pragma unroll
  for (int n = 0; n < 4; ++n)
#pragma unroll
    for (int m = 0; m < 4; ++m)
#pragma unroll
      for (int r = 0; r < 4; ++r) {
        size_t idx = (size_t)(rowbase + m * 16 + r) * HID + (colbase + n * 16);
        Cblk[idx] = acc[m][n][r];
      }
}

// GEMM2 (R16 verbatim, measured 39.6us): 128x192, BK=64, 4 waves, grid
// 512 = 2/CU, 80 KB LDS. Row&7 swizzle. bias + sigmoid, NT f32 store.
__global__ __launch_bounds__(256) void gemm2s(
    const unsigned short* __restrict__ A, const unsigned short* __restrict__ B,
    const float* __restrict__ bias, float* __restrict__ Cout) {
  constexpr int BM = 128, BN = 192, BK = 64;
  constexpr int Kstride = HID;       // 1024
  constexpr int ntT = Kstride / BK;  // 16
  constexpr int nbn = IN_DIM / BN;   // 16
  constexpr int Nout = IN_DIM;

  __shared__ unsigned short As[2][BM * BK];  // 32 KB
  __shared__ unsigned short Bs[2][BN * BK];  // 48 KB

  const int tid = threadIdx.x;
  const int wave = tid >> 6;
  const int lane = tid & 63;
  const int wrow = wave >> 1, wcol = wave & 1;

  const int nwg = gridDim.x;  // 512
  const int swz = (blockIdx.x & 7) * (nwg >> 3) + (blockIdx.x >> 3);
  const int bn = swz % nbn;
  const int bm = swz / nbn;

  const unsigned short* Ablk = A + (size_t)bm * BM * Kstride;
  const unsigned short* Bblk = B + (size_t)bn * BN * Kstride;

  const int srow = tid >> 3;
  const int sgl = tid & 7;

  auto STAGE = [&](int buf, int k0) {
#pragma unroll
    for (int r = 0; r < 10; ++r) {
      if (r < 4) {
        const int rr = r * 32 + srow;
        const int g = sgl ^ (rr & 7);
        gload_lds16(Ablk + (size_t)rr * Kstride + k0 + g * 8,
                    (void*)&As[buf][r * 2048 + tid * 8]);
      } else {
        const int rr = (r - 4) * 32 + srow;
        const int g = sgl ^ (rr & 7);
        gload_lds16(Bblk + (size_t)rr * Kstride + k0 + g * 8,
                    (void*)&Bs[buf][(r - 4) * 2048 + tid * 8]);
      }
    }
  };

  const int fr = lane & 15;
  const int hi = lane >> 4;

  f32x4 acc[4][6] = {};

  STAGE(0, 0);
#pragma unroll 1
  for (int t = 0; t < ntT; ++t) {
    const int buf = t & 1;
    __syncthreads();
    if (t + 1 < ntT) STAGE(buf ^ 1, (t + 1) * BK);

    short8 af[4][2], bfr[6][2];
#pragma unroll
    for (int m = 0; m < 4; ++m) {
      const int row = wrow * 64 + m * 16 + fr;
#pragma unroll
      for (int kk = 0; kk < 2; ++kk) {
        const int g = (kk * 4 + hi) ^ (row & 7);
        af[m][kk] =
            *reinterpret_cast<const short8*>(&As[buf][row * BK + g * 8]);
      }
    }
#pragma unroll
    for (int n = 0; n < 6; ++n) {
      const int row = wcol * 96 + n * 16 + fr;
#pragma unroll
      for (int kk = 0; kk < 2; ++kk) {
        const int g = (kk * 4 + hi) ^ (row & 7);
        bfr[n][kk] =
            *reinterpret_cast<const short8*>(&Bs[buf][row * BK + g * 8]);
      }
    }
#pragma unroll
    for (int kk = 0; kk < 2; ++kk)
#pragma unroll
      for (int m = 0; m < 4; ++m)
#pragma unroll
        for (int n = 0; n < 6; ++n)
          acc[m][n] = __builtin_amdgcn_mfma_f32_16x16x32_bf16(
              af[m][kk], bfr[n][kk], acc[m][n], 0, 0, 0);
  }

  const int rowbase = bm * BM + wrow * 64 + hi * 4;
  const int colbase = bn * BN + wcol * 96 + fr;
#pragma unroll
  for (int n = 0; n < 6; ++n) {
    const float bv = bias[colbase + n * 16];
#pragma unroll
    for (int m = 0; m < 4; ++m)
#pragma unroll
      for (int r = 0; r < 4; ++r) {
        float v = acc[m][n][r] + bv;
        v = 1.0f / (1.0f + __expf(-v));
        size_t idx = (size_t)(rowbase + m * 16 + r) * Nout + (colbase + n * 16);
        __builtin_nontemporal_store(v, &Cout[idx]);
      }
  }
}

extern "C" void kernel_launch(void* const* d_in, const int* in_sizes, int n_in,
                              void* d_out, int out_size, void* d_ws,
                              size_t ws_size, hipStream_t stream) {
  const float* x = (const float*)d_in[0];
  const float* We = (const float*)d_in[1];
  const float* be = (const float*)d_in[2];
  const float* Wd = (const float*)d_in[3];
  const float* bd = (const float*)d_in[4];

  float* out = (float*)d_out;                 // [4096,3072]
  float* hid = out + (size_t)BATCH * IN_DIM;  // [4096,1024]
  // split-K=3 f32 partials: 3 x 16.78MB = 50.3MB = exactly the out region.
  // ode consumes them; GEMM2 overwrites the region last. hid region clean.
  float* part = out;

  unsigned short* Web = (unsigned short*)d_ws;         // bf16 We  [1024,3072]
  unsigned short* Wdb = Web + (size_t)HID * IN_DIM;    // bf16 Wd  [3072,1024]
  unsigned short* hb = Wdb + (size_t)IN_DIM * HID;     // bf16 hid [4096,1024]

  cvt2_kernel<<<1024, 256, 0, stream>>>(We, Wd, Web, Wdb, HID * IN_DIM / 4,
                                        IN_DIM * HID / 4);

  // GEMM1: f32-A direct staging, split-K=3 -> 768 blocks = 3/CU resident
  gemm1f<<<768, 256, 0, stream>>>(x, Web, part);

  // ODE: gamma = p0+p1+p2+be, RK4 -> hid f32 (NT) + hb bf16
  ode3_kernel<<<2048, 256, 0, stream>>>(part, be, hid, hb, BATCH * HID / 4);

  // GEMM2: out = sigmoid(y @ Wd^T + bd). 128x192, BK=64 -> 512 blocks = 2/CU
  gemm2s<<<512, 256, 0, stream>>>(hb, Wdb, bd, out);
}

// Round 20
// 102.014 us; speedup vs baseline: 1.1726x; 1.1238x over previous
//
#include <hip/hip_runtime.h>
#include <hip/hip_bf16.h>

#define BATCH 4096
#define IN_DIM 3072
#define HID 1024
#define NSTEP 6

typedef __attribute__((ext_vector_type(8))) short short8;
typedef __attribute__((ext_vector_type(4))) float f32x4;
typedef __attribute__((ext_vector_type(4))) unsigned short ushort4v;

__device__ __forceinline__ void gload_lds16(const void* g, void* lds) {
  __builtin_amdgcn_global_load_lds(
      (const __attribute__((address_space(1))) void*)g,
      (__attribute__((address_space(3))) void*)lds, 16, 0, 0);
}

__device__ __forceinline__ unsigned short f32_to_bf16(float f) {
  unsigned int u = __builtin_bit_cast(unsigned int, f);
  unsigned int r = u + 0x7fffu + ((u >> 16) & 1u);
  return (unsigned short)(r >> 16);
}

__device__ __forceinline__ float bf16_to_f32(unsigned short u) {
  return __builtin_bit_cast(float, (unsigned int)u << 16);
}

// fused f32 -> bf16 conversion of x, We, Wd (one launch)
__global__ void cvt3_kernel(const float* __restrict__ a,
                            const float* __restrict__ b,
                            const float* __restrict__ c,
                            unsigned short* __restrict__ da,
                            unsigned short* __restrict__ db,
                            unsigned short* __restrict__ dc, int na, int nb,
                            int nc) {
  const int total = na + nb + nc;
  const int stride = gridDim.x * blockDim.x;
  for (int i = blockIdx.x * blockDim.x + threadIdx.x; i < total; i += stride) {
    const float* s;
    unsigned short* d;
    int j = i;
    if (j < na) {
      s = a; d = da;
    } else if (j < na + nb) {
      s = b; d = db; j -= na;
    } else {
      s = c; d = dc; j -= na + nb;
    }
    const float4 v = reinterpret_cast<const float4*>(s)[j];
    ushort4v o;
    o.x = f32_to_bf16(v.x);
    o.y = f32_to_bf16(v.y);
    o.z = f32_to_bf16(v.z);
    o.w = f32_to_bf16(v.w);
    reinterpret_cast<ushort4v*>(d)[j] = o;
  }
}

// Split-K2 reduce of BF16 partials (p0+p1+bias) + RK4 nmODE.
// Writes y f32 (NT) + bf16 copy for GEMM2.
__global__ __launch_bounds__(256) void ode_kernel(
    const unsigned short* __restrict__ part, const float* __restrict__ be,
    float* __restrict__ hid, unsigned short* __restrict__ hb, int n4) {
  const float dt = 1.0f / (float)NSTEP;
  const float h2 = 0.5f * dt, hd = dt, h6 = dt / 6.0f;
  const size_t seg = (size_t)BATCH * HID / 4;  // ushort4 units per partial
  const ushort4v* p4 = reinterpret_cast<const ushort4v*>(part);
  int stride = gridDim.x * blockDim.x;
  for (int i = blockIdx.x * blockDim.x + threadIdx.x; i < n4; i += stride) {
    const ushort4v a4 = p4[i];
    const ushort4v b4 = p4[i + seg];
    const float4 e4 = reinterpret_cast<const float4*>(be)[i & (HID / 4 - 1)];
    float g[4];
#pragma unroll
    for (int e = 0; e < 4; ++e)
      g[e] = bf16_to_f32(a4[e]) + bf16_to_f32(b4[e]);
    g[0] += e4.x; g[1] += e4.y; g[2] += e4.z; g[3] += e4.w;
    float y[4] = {0.0f, 0.0f, 0.0f, 0.0f};
#pragma unroll 1
    for (int s = 0; s < NSTEP; ++s) {
      float k1[4], k2[4], k3[4], k4[4];
#pragma unroll
      for (int e = 0; e < 4; ++e) {
        float t = __sinf(y[e] + g[e]);
        k1[e] = t * t - y[e];
      }
#pragma unroll
      for (int e = 0; e < 4; ++e) {
        float yy = fmaf(h2, k1[e], y[e]);
        float t = __sinf(yy + g[e]);
        k2[e] = t * t - yy;
      }
#pragma unroll
      for (int e = 0; e < 4; ++e) {
        float yy = fmaf(h2, k2[e], y[e]);
        float t = __sinf(yy + g[e]);
        k3[e] = t * t - yy;
      }
#pragma unroll
      for (int e = 0; e < 4; ++e) {
        float yy = fmaf(hd, k3[e], y[e]);
        float t = __sinf(yy + g[e]);
        k4[e] = t * t - yy;
      }
#pragma unroll
      for (int e = 0; e < 4; ++e) {
        float ks = k1[e] + 2.0f * (k2[e] + k3[e]) + k4[e];
        y[e] = fmaf(h6, ks, y[e]);
      }
    }
    f32x4 o4;
    o4[0] = y[0]; o4[1] = y[1]; o4[2] = y[2]; o4[3] = y[3];
    __builtin_nontemporal_store(o4, &reinterpret_cast<f32x4*>(hid)[i]);
    ushort4v ob;
    ob.x = f32_to_bf16(y[0]);
    ob.y = f32_to_bf16(y[1]);
    ob.z = f32_to_bf16(y[2]);
    ob.w = f32_to_bf16(y[3]);
    reinterpret_cast<ushort4v*>(hb)[i] = ob;
  }
}

// GEMM1 (R15/R16 structure, measured ~35us): specialized 2-phase, BK=64,
// 128x128 tile, 4 waves, split-K=2 -> 512 blocks = 2/CU. Row&7 swizzle.
// BF16 partial at Pout + sk*BATCH*HID — CACHED stores (not NT): 16-lane
// 32B segments coalesce in L2, logical 16.8MB writes (R9's 66MB came
// from NT partial-line bypass).
__global__ __launch_bounds__(256) void gemm1s(
    const unsigned short* __restrict__ A, const unsigned short* __restrict__ B,
    unsigned short* __restrict__ Pout) {
  constexpr int BM = 128, BN = 128, BK = 64;
  constexpr int Kstride = IN_DIM;    // 3072
  constexpr int Klen = Kstride / 2;  // 1536
  constexpr int ntT = Klen / BK;     // 24
  constexpr int nbn = HID / BN;      // 8
  constexpr int nbm = BATCH / BM;    // 32
  constexpr int tiles = nbm * nbn;   // 256

  __shared__ unsigned short As[2][BM * BK];
  __shared__ unsigned short Bs[2][BN * BK];

  const int tid = threadIdx.x;
  const int wave = tid >> 6;
  const int lane = tid & 63;
  const int wrow = wave >> 1, wcol = wave & 1;

  const int nwg = gridDim.x;  // 512
  const int swz = (blockIdx.x & 7) * (nwg >> 3) + (blockIdx.x >> 3);
  const int sk = swz / tiles;
  const int rem = swz % tiles;
  const int bn = rem % nbn;
  const int bm = rem / nbn;

  const unsigned short* Ablk = A + (size_t)bm * BM * Kstride + sk * Klen;
  const unsigned short* Bblk = B + (size_t)bn * BN * Kstride + sk * Klen;

  const int srow = tid >> 3;  // 0..31: row within a 32-row stage round
  const int sgl = tid & 7;    // logical 16B granule (8 per 64-col row)

  auto STAGE = [&](int buf, int k0) {
#pragma unroll
    for (int r = 0; r < 8; ++r) {
      const int rr = (r & 3) * 32 + srow;
      const int g = sgl ^ (rr & 7);  // inverse-swizzled global source
      if (r < 4)
        gload_lds16(Ablk + (size_t)rr * Kstride + k0 + g * 8,
                    (void*)&As[buf][(r & 3) * 2048 + tid * 8]);
      else
        gload_lds16(Bblk + (size_t)rr * Kstride + k0 + g * 8,
                    (void*)&Bs[buf][(r & 3) * 2048 + tid * 8]);
    }
  };

  const int fr = lane & 15;
  const int hi = lane >> 4;

  f32x4 acc[4][4] = {};

  STAGE(0, 0);
#pragma unroll 1
  for (int t = 0; t < ntT; ++t) {
    const int buf = t & 1;
    __syncthreads();
    if (t + 1 < ntT) STAGE(buf ^ 1, (t + 1) * BK);

    short8 af[4][2], bfr[4][2];
#pragma unroll
    for (int m = 0; m < 4; ++m) {
      const int row = wrow * 64 + m * 16 + fr;
#pragma unroll
      for (int kk = 0; kk < 2; ++kk) {
        const int g = (kk * 4 + hi) ^ (row & 7);
        af[m][kk] =
            *reinterpret_cast<const short8*>(&As[buf][row * BK + g * 8]);
      }
    }
#pragma unroll
    for (int n = 0; n < 4; ++n) {
      const int row = wcol * 64 + n * 16 + fr;
#pragma unroll
      for (int kk = 0; kk < 2; ++kk) {
        const int g = (kk * 4 + hi) ^ (row & 7);
        bfr[n][kk] =
            *reinterpret_cast<const short8*>(&Bs[buf][row * BK + g * 8]);
      }
    }
#pragma unroll
    for (int kk = 0; kk < 2; ++kk)
#pragma unroll
      for (int m = 0; m < 4; ++m)
#pragma unroll
        for (int n = 0; n < 4; ++n)
          acc[m][n] = __builtin_amdgcn_mfma_f32_16x16x32_bf16(
              af[m][kk], bfr[n][kk], acc[m][n], 0, 0, 0);
  }

  // epilogue: bf16 partial, cached store (L2 coalesces 32B segments)
  const int rowbase = bm * BM + wrow * 64 + hi * 4;
  const int colbase = bn * BN + wcol * 64 + fr;
  unsigned short* Pblk = Pout + (size_t)sk * BATCH * HID;
#pragma unroll
  for (int n = 0; n < 4; ++n)
#pragma unroll
    for (int m = 0; m < 4; ++m)
#pragma unroll
      for (int r = 0; r < 4; ++r) {
        size_t idx = (size_t)(rowbase + m * 16 + r) * HID + (colbase + n * 16);
        Pblk[idx] = f32_to_bf16(acc[m][n][r]);
      }
}

// GEMM2 (R16 verbatim, measured 39.6us): 128x192, BK=64, 4 waves, grid
// 512 = 2/CU, 80 KB LDS. Row&7 swizzle. bias + sigmoid, NT f32 store.
__global__ __launch_bounds__(256) void gemm2s(
    const unsigned short* __restrict__ A, const unsigned short* __restrict__ B,
    const float* __restrict__ bias, float* __restrict__ Cout) {
  constexpr int BM = 128, BN = 192, BK = 64;
  constexpr int Kstride = HID;       // 1024
  constexpr int ntT = Kstride / BK;  // 16
  constexpr int nbn = IN_DIM / BN;   // 16
  constexpr int Nout = IN_DIM;

  __shared__ unsigned short As[2][BM * BK];  // 32 KB
  __shared__ unsigned short Bs[2][BN * BK];  // 48 KB

  const int tid = threadIdx.x;
  const int wave = tid >> 6;
  const int lane = tid & 63;
  const int wrow = wave >> 1, wcol = wave & 1;

  const int nwg = gridDim.x;  // 512
  const int swz = (blockIdx.x & 7) * (nwg >> 3) + (blockIdx.x >> 3);
  const int bn = swz % nbn;
  const int bm = swz / nbn;

  const unsigned short* Ablk = A + (size_t)bm * BM * Kstride;
  const unsigned short* Bblk = B + (size_t)bn * BN * Kstride;

  const int srow = tid >> 3;
  const int sgl = tid & 7;

  auto STAGE = [&](int buf, int k0) {
#pragma unroll
    for (int r = 0; r < 10; ++r) {
      if (r < 4) {
        const int rr = r * 32 + srow;
        const int g = sgl ^ (rr & 7);
        gload_lds16(Ablk + (size_t)rr * Kstride + k0 + g * 8,
                    (void*)&As[buf][r * 2048 + tid * 8]);
      } else {
        const int rr = (r - 4) * 32 + srow;
        const int g = sgl ^ (rr & 7);
        gload_lds16(Bblk + (size_t)rr * Kstride + k0 + g * 8,
                    (void*)&Bs[buf][(r - 4) * 2048 + tid * 8]);
      }
    }
  };

  const int fr = lane & 15;
  const int hi = lane >> 4;

  f32x4 acc[4][6] = {};

  STAGE(0, 0);
#pragma unroll 1
  for (int t = 0; t < ntT; ++t) {
    const int buf = t & 1;
    __syncthreads();
    if (t + 1 < ntT) STAGE(buf ^ 1, (t + 1) * BK);

    short8 af[4][2], bfr[6][2];
#pragma unroll
    for (int m = 0; m < 4; ++m) {
      const int row = wrow * 64 + m * 16 + fr;
#pragma unroll
      for (int kk = 0; kk < 2; ++kk) {
        const int g = (kk * 4 + hi) ^ (row & 7);
        af[m][kk] =
            *reinterpret_cast<const short8*>(&As[buf][row * BK + g * 8]);
      }
    }
#pragma unroll
    for (int n = 0; n < 6; ++n) {
      const int row = wcol * 96 + n * 16 + fr;
#pragma unroll
      for (int kk = 0; kk < 2; ++kk) {
        const int g = (kk * 4 + hi) ^ (row & 7);
        bfr[n][kk] =
            *reinterpret_cast<const short8*>(&Bs[buf][row * BK + g * 8]);
      }
    }
#pragma unroll
    for (int kk = 0; kk < 2; ++kk)
#pragma unroll
      for (int m = 0; m < 4; ++m)
#pragma unroll
        for (int n = 0; n < 6; ++n)
          acc[m][n] = __builtin_amdgcn_mfma_f32_16x16x32_bf16(
              af[m][kk], bfr[n][kk], acc[m][n], 0, 0, 0);
  }

  const int rowbase = bm * BM + wrow * 64 + hi * 4;
  const int colbase = bn * BN + wcol * 96 + fr;
#pragma unroll
  for (int n = 0; n < 6; ++n) {
    const float bv = bias[colbase + n * 16];
#pragma unroll
    for (int m = 0; m < 4; ++m)
#pragma unroll
      for (int r = 0; r < 4; ++r) {
        float v = acc[m][n][r] + bv;
        v = 1.0f / (1.0f + __expf(-v));
        size_t idx = (size_t)(rowbase + m * 16 + r) * Nout + (colbase + n * 16);
        __builtin_nontemporal_store(v, &Cout[idx]);
      }
  }
}

extern "C" void kernel_launch(void* const* d_in, const int* in_sizes, int n_in,
                              void* d_out, int out_size, void* d_ws,
                              size_t ws_size, hipStream_t stream) {
  const float* x = (const float*)d_in[0];
  const float* We = (const float*)d_in[1];
  const float* be = (const float*)d_in[2];
  const float* Wd = (const float*)d_in[3];
  const float* bd = (const float*)d_in[4];

  float* out = (float*)d_out;                 // [4096,3072]
  float* hid = out + (size_t)BATCH * IN_DIM;  // [4096,1024]
  // split-K=2 bf16 partials (16.8MB) in the out region (50MB); GEMM2 last.
  unsigned short* part = (unsigned short*)out;

  unsigned short* xb = (unsigned short*)d_ws;          // bf16 x   [4096,3072]
  unsigned short* Web = xb + (size_t)BATCH * IN_DIM;   // bf16 We  [1024,3072]
  unsigned short* Wdb = Web + (size_t)HID * IN_DIM;    // bf16 Wd  [3072,1024]
  unsigned short* hb = Wdb + (size_t)IN_DIM * HID;     // bf16 hid [4096,1024]

  cvt3_kernel<<<2048, 256, 0, stream>>>(
      x, We, Wd, xb, Web, Wdb, BATCH * IN_DIM / 4, HID * IN_DIM / 4,
      IN_DIM * HID / 4);

  // GEMM1: specialized 2-phase BK=64, bf16 partials of x @ We^T. split-K=2,
  // 512 blocks = 2/CU fully resident.
  gemm1s<<<512, 256, 0, stream>>>(xb, Web, part);

  // ODE: gamma = p0+p1+be, RK4 -> hid f32 (NT) + hb bf16
  ode_kernel<<<2048, 256, 0, stream>>>(part, be, hid, hb, BATCH * HID / 4);

  // GEMM2: out = sigmoid(y @ Wd^T + bd). 128x192, BK=64 -> 512 blocks = 2/CU
  gemm2s<<<512, 256, 0, stream>>>(hb, Wdb, bd, out);
}